// Round 3
// baseline (943.195 us; speedup 1.0000x reference)
//
#include <hip/hip_runtime.h>

// ---------------------------------------------------------------------------
// LIIF forward, MI355X.  ALL tensors are float32 (per reference source).
// prep_kernel: weight repack f32->f16; layer0 rows permuted f' = k*64+c
//   (k=3x3 patch idx, c=channel) and padded 580->608; w4 N padded 3->16.
// conv_kernel: 3x3 conv (3->64) + bias + tanh -> padded map P[2][98][98][64].
// liif_main:  per 64 queries x 4 corner offsets, gather + 5-layer MLP via
//   mfma_f32_16x16x32_f16, transposed orientation D = W^T x^T, area blend.
// Index math in f32 (bit-matches np ref); activations f16, accum f32.
// R3: I/O dtype flipped bf16 -> f32 (reference declares jnp.float32; the
//   R1/R2 NaNs matched the f32-misread-as-bf16 signature via s_area).
// ---------------------------------------------------------------------------

typedef _Float16 half8   __attribute__((ext_vector_type(8)));
typedef _Float16 half4v  __attribute__((ext_vector_type(4)));
typedef float    float4v __attribute__((ext_vector_type(4)));

// clamped f32->f16: also squashes NaN (fmax/fmin return the non-NaN operand)
__device__ __forceinline__ _Float16 to_h(float v) {
  return (_Float16)fminf(fmaxf(v, -60000.0f), 60000.0f);
}

#define NQ 30000
#define QT 469  // ceil(NQ/64)

// ---------------- weight repack --------------------------------------------
// wp layout: [kb][n][8] f16, element (n, k=kb*8+i) at ((kb*N + n)*8 + i).
__global__ void prep_kernel(const float* __restrict__ w0,
                            const float* __restrict__ w1,
                            const float* __restrict__ w2,
                            const float* __restrict__ w3,
                            const float* __restrict__ w4,
                            _Float16* __restrict__ p0, _Float16* __restrict__ p1,
                            _Float16* __restrict__ p2, _Float16* __restrict__ p3,
                            _Float16* __restrict__ p4) {
  int idx = blockIdx.x * 256 + threadIdx.x;
  if (idx < 155648) {                      // wp0: 76 kb * 256 n * 8
    int kb = idx >> 11, rem = idx & 2047;
    int n = rem >> 3, i = rem & 7;
    int f = kb * 8 + i;                    // permuted feature index
    float v = 0.0f;
    if (f < 576)      v = w0[((f & 63) * 9 + (f >> 6)) * 256 + n];
    else if (f < 580) v = w0[f * 256 + n];
    p0[idx] = (_Float16)v;
  } else if (idx < 352256) {               // wp1..3: 3 * 32kb * 256 * 8
    int j = idx - 155648;
    int l = j >> 16;
    int j2 = j & 65535;
    int kb = j2 >> 11, rem = j2 & 2047;
    int n = rem >> 3, i = rem & 7;
    int k = kb * 8 + i;
    const float* w = (l == 0) ? w1 : (l == 1) ? w2 : w3;
    _Float16* p = (l == 0) ? p1 : (l == 1) ? p2 : p3;
    p[j2] = (_Float16)w[k * 256 + n];
  } else if (idx < 356352) {               // wp4: 32kb * 16 * 8
    int j = idx - 352256;
    int kb = j >> 7, rem = j & 127;
    int n = rem >> 3, i = rem & 7;
    int k = kb * 8 + i;
    float v = (n < 3) ? w4[k * 3 + n] : 0.0f;
    p4[j] = (_Float16)v;
  }
}

// ---------------- conv 3x3 (3->64) + bias + tanh, zero-padded borders ------
__global__ void conv_kernel(const float* __restrict__ inp,
                            const float* __restrict__ cw,
                            const float* __restrict__ cb,
                            _Float16* __restrict__ P) {
  __shared__ __align__(16) float s_w[1728];
  __shared__ __align__(16) float s_b[64];
  for (int i = threadIdx.x; i < 1728; i += 256) s_w[i] = cw[i];
  if (threadIdx.x < 64) s_b[threadIdx.x] = cb[threadIdx.x];
  __syncthreads();
  int tid = blockIdx.x * 256 + threadIdx.x;
  if (tid >= 2 * 98 * 98) return;
  int b = tid / 9604;
  int rem = tid % 9604;
  int yy = rem / 98, xx = rem % 98;
  alignas(16) _Float16 outv[64];
  if (yy == 0 || yy == 97 || xx == 0 || xx == 97) {
#pragma unroll
    for (int c = 0; c < 64; ++c) outv[c] = (_Float16)0.0f;
  } else {
    int y = yy - 1, x = xx - 1;
    float win[27];
#pragma unroll
    for (int ci = 0; ci < 3; ++ci)
#pragma unroll
      for (int ky = 0; ky < 3; ++ky)
#pragma unroll
        for (int kx = 0; kx < 3; ++kx) {
          int yi = y + ky - 1, xi = x + kx - 1;
          float v = 0.0f;
          if (yi >= 0 && yi < 96 && xi >= 0 && xi < 96)
            v = inp[((b * 3 + ci) * 96 + yi) * 96 + xi];
          win[ci * 9 + ky * 3 + kx] = v;
        }
    for (int co = 0; co < 64; ++co) {
      float acc = s_b[co];
#pragma unroll
      for (int k = 0; k < 27; ++k) acc = fmaf(win[k], s_w[co * 27 + k], acc);
      outv[co] = (_Float16)tanhf(acc);
    }
  }
  _Float16* dst = P + tid * 64;
#pragma unroll
  for (int j = 0; j < 8; ++j) ((half8*)dst)[j] = ((const half8*)outv)[j];
}

// ---------------- main: gather + MLP + blend -------------------------------
// One WG = 256 thr = 4 waves = 64 queries of one batch. Transposed GEMMs:
// D[ch][row] = sum_k W[k][ch] * x[row][k]; A = packed weights, B = act rows.
__device__ __forceinline__ void writeback(float4v (&acc)[4][4],
                                          const float* __restrict__ bias,
                                          _Float16 (*s_h)[264],
                                          int wv, int lg, int ln) {
#pragma unroll
  for (int mt = 0; mt < 4; ++mt) {
    const int ch0 = wv * 64 + mt * 16 + lg * 4;
    float bb0 = bias[ch0 + 0];
    float bb1 = bias[ch0 + 1];
    float bb2 = bias[ch0 + 2];
    float bb3 = bias[ch0 + 3];
#pragma unroll
    for (int nt = 0; nt < 4; ++nt) {
      const int r = nt * 16 + ln;
      half4v hv;
      hv[0] = to_h(fmaxf(acc[mt][nt][0] + bb0, 0.0f));
      hv[1] = to_h(fmaxf(acc[mt][nt][1] + bb1, 0.0f));
      hv[2] = to_h(fmaxf(acc[mt][nt][2] + bb2, 0.0f));
      hv[3] = to_h(fmaxf(acc[mt][nt][3] + bb3, 0.0f));
      *(half4v*)(&s_h[r][ch0]) = hv;
    }
  }
}

__global__ __launch_bounds__(256, 3) void liif_main(
    const float* __restrict__ coord, const float* __restrict__ cell,
    const float* __restrict__ bias0, const float* __restrict__ bias1,
    const float* __restrict__ bias2, const float* __restrict__ bias3,
    const float* __restrict__ bias4,
    const _Float16* __restrict__ P,
    const _Float16* __restrict__ wp0, const _Float16* __restrict__ wp1,
    const _Float16* __restrict__ wp2, const _Float16* __restrict__ wp3,
    const _Float16* __restrict__ wp4,
    float* __restrict__ out) {
  __shared__ __align__(16) int      s_pix[4][64];
  __shared__ __align__(16) float    s_area[4][64];
  __shared__ __align__(16) _Float16 s_ext[4][64][8];
  __shared__ __align__(16) float    s_num[64][4];
  __shared__ __align__(16) _Float16 s_h[64][264]; // 264: 132 dw = 4 mod 32

  const int t  = threadIdx.x;
  const int bb = blockIdx.x / QT;
  const int q0 = (blockIdx.x % QT) * 64;

  // ---- phase 0: per-row meta for all 4 offsets (f32, matches np) ----
  if (t < 64) {
    int q = q0 + t;
    bool valid = q < NQ;
    float c0 = 0.f, c1 = 0.f, e0 = 0.f, e1 = 0.f;
    if (valid) {
      int base = (bb * NQ + q) * 2;
      c0 = coord[base]; c1 = coord[base + 1];
      e0 = cell[base];  e1 = cell[base + 1];
    }
    float rc0 = e0 * 96.0f, rc1 = e1 * 96.0f;
#pragma unroll
    for (int o = 0; o < 4; ++o) {
      float oy = (o < 2) ? -1.0f : 1.0f;     // offsets [-1,-1],[-1,1],[1,-1],[1,1]
      float ox = (o & 1) ? 1.0f : -1.0f;
      float ec0 = (c0 + oy * (1.0f / 96.0f)) + 1e-6f;
      float ec1 = (c1 + ox * (1.0f / 96.0f)) + 1e-6f;
      ec0 = fminf(fmaxf(ec0, -1.0f), 1.0f);  // f32(-1+1e-10) == -1.0f
      ec1 = fminf(fmaxf(ec1, -1.0f), 1.0f);
      int iy = (int)rintf(((ec0 + 1.0f) * 96.0f) * 0.5f - 0.5f);  // half-even
      int ix = (int)rintf(((ec1 + 1.0f) * 96.0f) * 0.5f - 0.5f);
      iy = min(max(iy, 0), 95); ix = min(max(ix, 0), 95);
      float qc0 = -1.0f + (2.0f * (float)iy + 1.0f) / 96.0f;
      float qc1 = -1.0f + (2.0f * (float)ix + 1.0f) / 96.0f;
      float r0 = (c0 - qc0) * 96.0f;
      float r1 = (c1 - qc1) * 96.0f;
      s_pix[o][t]  = (bb * 98 + iy) * 98 + ix;   // padded pixel base
      s_area[o][t] = fabsf(r0 * r1) + 1e-9f;
      s_ext[o][t][0] = to_h(r0);  s_ext[o][t][1] = to_h(r1);
      s_ext[o][t][2] = to_h(rc0); s_ext[o][t][3] = to_h(rc1);
      s_ext[o][t][4] = (_Float16)0.0f; s_ext[o][t][5] = (_Float16)0.0f;
      s_ext[o][t][6] = (_Float16)0.0f; s_ext[o][t][7] = (_Float16)0.0f;
    }
    s_num[t][0] = 0.f; s_num[t][1] = 0.f; s_num[t][2] = 0.f; s_num[t][3] = 0.f;
  }
  __syncthreads();

  const int lane = t & 63;
  const int wv = t >> 6;
  const int ln = lane & 15;
  const int lg = lane >> 4;

  for (int o = 0; o < 4; ++o) {
    // ---------------- layer 0: K = 608 (9 blocks of 64 + extras) ----------
    float4v acc[4][4];
#pragma unroll
    for (int mt = 0; mt < 4; ++mt)
#pragma unroll
      for (int nt = 0; nt < 4; ++nt) { float4v z = {0.f,0.f,0.f,0.f}; acc[mt][nt] = z; }
    int pix[4];
#pragma unroll
    for (int nt = 0; nt < 4; ++nt) pix[nt] = s_pix[o][nt * 16 + ln];
    const int cbase = lg * 8;
    for (int s = 0; s < 19; ++s) {
      half8 bfr[4];
      if (s < 18) {
        int kb = s >> 1;
        int delta = (kb / 3) * 98 + (kb % 3);
        int coff = cbase + ((s & 1) << 5);
#pragma unroll
        for (int nt = 0; nt < 4; ++nt)
          bfr[nt] = *(const half8*)(P + (pix[nt] + delta) * 64 + coff);
      } else {
#pragma unroll
        for (int nt = 0; nt < 4; ++nt)
          bfr[nt] = *(const half8*)(&s_ext[o][nt * 16 + ln][0]);  // W rows >=580 are 0
      }
      half8 afr[4];
      const _Float16* pa = wp0 + (((s * 4 + lg) * 256) + wv * 64 + ln) * 8;
#pragma unroll
      for (int mt = 0; mt < 4; ++mt) afr[mt] = *(const half8*)(pa + mt * 128);
#pragma unroll
      for (int mt = 0; mt < 4; ++mt)
#pragma unroll
        for (int nt = 0; nt < 4; ++nt)
          acc[mt][nt] = __builtin_amdgcn_mfma_f32_16x16x32_f16(afr[mt], bfr[nt], acc[mt][nt], 0, 0, 0);
    }
    writeback(acc, bias0, s_h, wv, lg, ln);   // s_h not yet read this offset
    __syncthreads();

    // ---------------- layers 1..3: K = 256 --------------------------------
    for (int l = 0; l < 3; ++l) {
      const _Float16* wp = (l == 0) ? wp1 : (l == 1) ? wp2 : wp3;
      const float* bs = (l == 0) ? bias1 : (l == 1) ? bias2 : bias3;
#pragma unroll
      for (int mt = 0; mt < 4; ++mt)
#pragma unroll
        for (int nt = 0; nt < 4; ++nt) { float4v z = {0.f,0.f,0.f,0.f}; acc[mt][nt] = z; }
      for (int s = 0; s < 8; ++s) {
        half8 bfr[4];
#pragma unroll
        for (int nt = 0; nt < 4; ++nt)
          bfr[nt] = *(const half8*)(&s_h[nt * 16 + ln][s * 32 + lg * 8]);
        half8 afr[4];
        const _Float16* pa = wp + (((s * 4 + lg) * 256) + wv * 64 + ln) * 8;
#pragma unroll
        for (int mt = 0; mt < 4; ++mt) afr[mt] = *(const half8*)(pa + mt * 128);
#pragma unroll
        for (int mt = 0; mt < 4; ++mt)
#pragma unroll
          for (int nt = 0; nt < 4; ++nt)
            acc[mt][nt] = __builtin_amdgcn_mfma_f32_16x16x32_f16(afr[mt], bfr[nt], acc[mt][nt], 0, 0, 0);
      }
      __syncthreads();               // all reads of s_h done
      writeback(acc, bs, s_h, wv, lg, ln);
      __syncthreads();
    }

    // ---------------- layer 4: 256 -> 3 (padded 16); each wave 1 n-tile ---
    float4v a4 = {0.f, 0.f, 0.f, 0.f};
    for (int s = 0; s < 8; ++s) {
      half8 bfr = *(const half8*)(&s_h[wv * 16 + ln][s * 32 + lg * 8]);
      half8 afr = *(const half8*)(wp4 + (((s * 4 + lg) * 16) + ln) * 8);
      a4 = __builtin_amdgcn_mfma_f32_16x16x32_f16(afr, bfr, a4, 0, 0, 0);
    }
    if (lg == 0) {                   // lanes 0..15 hold out-ch 0..3 (regs 0..3)
      int r = wv * 16 + ln;
      float aw = s_area[3 - o][r];   // areas reversed across offsets
      float4v cur = *(float4v*)(&s_num[r][0]);
      cur[0] += a4[0] * aw; cur[1] += a4[1] * aw; cur[2] += a4[2] * aw;
      *(float4v*)(&s_num[r][0]) = cur;
    }
    __syncthreads();                 // s_h / s_num stable before next offset
  }

  // ---- final: out = tanh(num/den + b4) * 1.01, f32 ----
  if (t < 64) {
    int q = q0 + t;
    if (q < NQ) {
      float den = s_area[0][t] + s_area[1][t] + s_area[2][t] + s_area[3][t];
      int ob = (bb * NQ + q) * 3;
#pragma unroll
      for (int j = 0; j < 3; ++j) {
        float v = s_num[t][j] / den + bias4[j];
        out[ob + j] = tanhf(v) * 1.01f;
      }
    }
  }
}

// ---------------------------------------------------------------------------
extern "C" void kernel_launch(void* const* d_in, const int* in_sizes, int n_in,
                              void* d_out, int out_size, void* d_ws, size_t ws_size,
                              hipStream_t stream) {
  const float* inp   = (const float*)d_in[0];
  const float* coord = (const float*)d_in[1];
  const float* cell  = (const float*)d_in[2];
  const float* cw    = (const float*)d_in[3];
  const float* cb    = (const float*)d_in[4];
  const float* w0    = (const float*)d_in[5];
  const float* b0    = (const float*)d_in[6];
  const float* w1    = (const float*)d_in[7];
  const float* b1    = (const float*)d_in[8];
  const float* w2    = (const float*)d_in[9];
  const float* b2    = (const float*)d_in[10];
  const float* w3    = (const float*)d_in[11];
  const float* b3    = (const float*)d_in[12];
  const float* w4    = (const float*)d_in[13];
  const float* b4    = (const float*)d_in[14];

  char* ws = (char*)d_ws;
  _Float16* P   = (_Float16*)(ws);            // 2,458,624 B
  _Float16* wp0 = (_Float16*)(ws + 2458624);  //   311,296 B
  _Float16* wp1 = (_Float16*)(ws + 2769920);  //   131,072 B
  _Float16* wp2 = (_Float16*)(ws + 2900992);
  _Float16* wp3 = (_Float16*)(ws + 3032064);
  _Float16* wp4 = (_Float16*)(ws + 3163136);  //     8,192 B
  float* outp = (float*)d_out;

  hipLaunchKernelGGL(prep_kernel, dim3(1392), dim3(256), 0, stream,
                     w0, w1, w2, w3, w4, wp0, wp1, wp2, wp3, wp4);
  hipLaunchKernelGGL(conv_kernel, dim3(76), dim3(256), 0, stream, inp, cw, cb, P);
  hipLaunchKernelGGL(liif_main, dim3(2 * QT), dim3(256), 0, stream,
                     coord, cell, b0, b1, b2, b3, b4,
                     P, wp0, wp1, wp2, wp3, wp4, outp);
}

// Round 4
// 438.444 us; speedup vs baseline: 2.1512x; 2.1512x over previous
//
#include <hip/hip_runtime.h>

// ---------------------------------------------------------------------------
// LIIF forward, MI355X.  ALL tensors are float32 (per reference source).
// prep_kernel: weight repack f32->f16; layer0 rows permuted f' = k*64+c
//   (k=3x3 patch idx, c=channel) and padded 580->608; w4 N padded 3->16.
// conv_kernel: 3x3 conv (3->64) + bias + tanh -> padded map P[2][98][98][64].
// liif_main:  per 64 queries x 4 corner offsets, gather + 5-layer MLP via
//   mfma_f32_16x16x32_f16, transposed orientation D = W^T x^T, area blend.
// Index math in f32 (bit-matches np ref); activations f16, accum f32.
// R4: __launch_bounds__(256,3) -> (256,2).  R3 counters showed 444 MB
//   WRITE_SIZE / 982 MB FETCH_SIZE = massive scratch spills (budget 168
//   regs @ 3 waves/EU < ~200 peak pressure) thrashing L2 and poisoning the
//   layer-0 gathers.  Budget 256 @ 2 waves/EU removes all spills; unroll
//   pragmas pin the o/layer loops rolled so pressure stays bounded.
// ---------------------------------------------------------------------------

typedef _Float16 half8   __attribute__((ext_vector_type(8)));
typedef _Float16 half4v  __attribute__((ext_vector_type(4)));
typedef float    float4v __attribute__((ext_vector_type(4)));

// clamped f32->f16: also squashes NaN (fmax/fmin return the non-NaN operand)
__device__ __forceinline__ _Float16 to_h(float v) {
  return (_Float16)fminf(fmaxf(v, -60000.0f), 60000.0f);
}

#define NQ 30000
#define QT 469  // ceil(NQ/64)

// ---------------- weight repack --------------------------------------------
// wp layout: [kb][n][8] f16, element (n, k=kb*8+i) at ((kb*N + n)*8 + i).
__global__ void prep_kernel(const float* __restrict__ w0,
                            const float* __restrict__ w1,
                            const float* __restrict__ w2,
                            const float* __restrict__ w3,
                            const float* __restrict__ w4,
                            _Float16* __restrict__ p0, _Float16* __restrict__ p1,
                            _Float16* __restrict__ p2, _Float16* __restrict__ p3,
                            _Float16* __restrict__ p4) {
  int idx = blockIdx.x * 256 + threadIdx.x;
  if (idx < 155648) {                      // wp0: 76 kb * 256 n * 8
    int kb = idx >> 11, rem = idx & 2047;
    int n = rem >> 3, i = rem & 7;
    int f = kb * 8 + i;                    // permuted feature index
    float v = 0.0f;
    if (f < 576)      v = w0[((f & 63) * 9 + (f >> 6)) * 256 + n];
    else if (f < 580) v = w0[f * 256 + n];
    p0[idx] = (_Float16)v;
  } else if (idx < 352256) {               // wp1..3: 3 * 32kb * 256 * 8
    int j = idx - 155648;
    int l = j >> 16;
    int j2 = j & 65535;
    int kb = j2 >> 11, rem = j2 & 2047;
    int n = rem >> 3, i = rem & 7;
    int k = kb * 8 + i;
    const float* w = (l == 0) ? w1 : (l == 1) ? w2 : w3;
    _Float16* p = (l == 0) ? p1 : (l == 1) ? p2 : p3;
    p[j2] = (_Float16)w[k * 256 + n];
  } else if (idx < 356352) {               // wp4: 32kb * 16 * 8
    int j = idx - 352256;
    int kb = j >> 7, rem = j & 127;
    int n = rem >> 3, i = rem & 7;
    int k = kb * 8 + i;
    float v = (n < 3) ? w4[k * 3 + n] : 0.0f;
    p4[j] = (_Float16)v;
  }
}

// ---------------- conv 3x3 (3->64) + bias + tanh, zero-padded borders ------
__global__ void conv_kernel(const float* __restrict__ inp,
                            const float* __restrict__ cw,
                            const float* __restrict__ cb,
                            _Float16* __restrict__ P) {
  __shared__ __align__(16) float s_w[1728];
  __shared__ __align__(16) float s_b[64];
  for (int i = threadIdx.x; i < 1728; i += 256) s_w[i] = cw[i];
  if (threadIdx.x < 64) s_b[threadIdx.x] = cb[threadIdx.x];
  __syncthreads();
  int tid = blockIdx.x * 256 + threadIdx.x;
  if (tid >= 2 * 98 * 98) return;
  int b = tid / 9604;
  int rem = tid % 9604;
  int yy = rem / 98, xx = rem % 98;
  alignas(16) _Float16 outv[64];
  if (yy == 0 || yy == 97 || xx == 0 || xx == 97) {
#pragma unroll
    for (int c = 0; c < 64; ++c) outv[c] = (_Float16)0.0f;
  } else {
    int y = yy - 1, x = xx - 1;
    float win[27];
#pragma unroll
    for (int ci = 0; ci < 3; ++ci)
#pragma unroll
      for (int ky = 0; ky < 3; ++ky)
#pragma unroll
        for (int kx = 0; kx < 3; ++kx) {
          int yi = y + ky - 1, xi = x + kx - 1;
          float v = 0.0f;
          if (yi >= 0 && yi < 96 && xi >= 0 && xi < 96)
            v = inp[((b * 3 + ci) * 96 + yi) * 96 + xi];
          win[ci * 9 + ky * 3 + kx] = v;
        }
    for (int co = 0; co < 64; ++co) {
      float acc = s_b[co];
#pragma unroll
      for (int k = 0; k < 27; ++k) acc = fmaf(win[k], s_w[co * 27 + k], acc);
      outv[co] = (_Float16)tanhf(acc);
    }
  }
  _Float16* dst = P + tid * 64;
#pragma unroll
  for (int j = 0; j < 8; ++j) ((half8*)dst)[j] = ((const half8*)outv)[j];
}

// ---------------- main: gather + MLP + blend -------------------------------
// One WG = 256 thr = 4 waves = 64 queries of one batch. Transposed GEMMs:
// D[ch][row] = sum_k W[k][ch] * x[row][k]; A = packed weights, B = act rows.
__device__ __forceinline__ void writeback(float4v (&acc)[4][4],
                                          const float* __restrict__ bias,
                                          _Float16 (*s_h)[264],
                                          int wv, int lg, int ln) {
#pragma unroll
  for (int mt = 0; mt < 4; ++mt) {
    const int ch0 = wv * 64 + mt * 16 + lg * 4;
    float bb0 = bias[ch0 + 0];
    float bb1 = bias[ch0 + 1];
    float bb2 = bias[ch0 + 2];
    float bb3 = bias[ch0 + 3];
#pragma unroll
    for (int nt = 0; nt < 4; ++nt) {
      const int r = nt * 16 + ln;
      half4v hv;
      hv[0] = to_h(fmaxf(acc[mt][nt][0] + bb0, 0.0f));
      hv[1] = to_h(fmaxf(acc[mt][nt][1] + bb1, 0.0f));
      hv[2] = to_h(fmaxf(acc[mt][nt][2] + bb2, 0.0f));
      hv[3] = to_h(fmaxf(acc[mt][nt][3] + bb3, 0.0f));
      *(half4v*)(&s_h[r][ch0]) = hv;
    }
  }
}

__global__ __launch_bounds__(256, 2) void liif_main(
    const float* __restrict__ coord, const float* __restrict__ cell,
    const float* __restrict__ bias0, const float* __restrict__ bias1,
    const float* __restrict__ bias2, const float* __restrict__ bias3,
    const float* __restrict__ bias4,
    const _Float16* __restrict__ P,
    const _Float16* __restrict__ wp0, const _Float16* __restrict__ wp1,
    const _Float16* __restrict__ wp2, const _Float16* __restrict__ wp3,
    const _Float16* __restrict__ wp4,
    float* __restrict__ out) {
  __shared__ __align__(16) int      s_pix[4][64];
  __shared__ __align__(16) float    s_area[4][64];
  __shared__ __align__(16) _Float16 s_ext[4][64][8];
  __shared__ __align__(16) float    s_num[64][4];
  __shared__ __align__(16) _Float16 s_h[64][264]; // 264: 132 dw = 4 mod 32

  const int t  = threadIdx.x;
  const int bb = blockIdx.x / QT;
  const int q0 = (blockIdx.x % QT) * 64;

  // ---- phase 0: per-row meta for all 4 offsets (f32, matches np) ----
  if (t < 64) {
    int q = q0 + t;
    bool valid = q < NQ;
    float c0 = 0.f, c1 = 0.f, e0 = 0.f, e1 = 0.f;
    if (valid) {
      int base = (bb * NQ + q) * 2;
      c0 = coord[base]; c1 = coord[base + 1];
      e0 = cell[base];  e1 = cell[base + 1];
    }
    float rc0 = e0 * 96.0f, rc1 = e1 * 96.0f;
#pragma unroll
    for (int o = 0; o < 4; ++o) {
      float oy = (o < 2) ? -1.0f : 1.0f;     // offsets [-1,-1],[-1,1],[1,-1],[1,1]
      float ox = (o & 1) ? 1.0f : -1.0f;
      float ec0 = (c0 + oy * (1.0f / 96.0f)) + 1e-6f;
      float ec1 = (c1 + ox * (1.0f / 96.0f)) + 1e-6f;
      ec0 = fminf(fmaxf(ec0, -1.0f), 1.0f);  // f32(-1+1e-10) == -1.0f
      ec1 = fminf(fmaxf(ec1, -1.0f), 1.0f);
      int iy = (int)rintf(((ec0 + 1.0f) * 96.0f) * 0.5f - 0.5f);  // half-even
      int ix = (int)rintf(((ec1 + 1.0f) * 96.0f) * 0.5f - 0.5f);
      iy = min(max(iy, 0), 95); ix = min(max(ix, 0), 95);
      float qc0 = -1.0f + (2.0f * (float)iy + 1.0f) / 96.0f;
      float qc1 = -1.0f + (2.0f * (float)ix + 1.0f) / 96.0f;
      float r0 = (c0 - qc0) * 96.0f;
      float r1 = (c1 - qc1) * 96.0f;
      s_pix[o][t]  = (bb * 98 + iy) * 98 + ix;   // padded pixel base
      s_area[o][t] = fabsf(r0 * r1) + 1e-9f;
      s_ext[o][t][0] = to_h(r0);  s_ext[o][t][1] = to_h(r1);
      s_ext[o][t][2] = to_h(rc0); s_ext[o][t][3] = to_h(rc1);
      s_ext[o][t][4] = (_Float16)0.0f; s_ext[o][t][5] = (_Float16)0.0f;
      s_ext[o][t][6] = (_Float16)0.0f; s_ext[o][t][7] = (_Float16)0.0f;
    }
    s_num[t][0] = 0.f; s_num[t][1] = 0.f; s_num[t][2] = 0.f; s_num[t][3] = 0.f;
  }
  __syncthreads();

  const int lane = t & 63;
  const int wv = t >> 6;
  const int ln = lane & 15;
  const int lg = lane >> 4;

#pragma unroll 1
  for (int o = 0; o < 4; ++o) {
    // ---------------- layer 0: K = 608 (9 blocks of 64 + extras) ----------
    float4v acc[4][4];
#pragma unroll
    for (int mt = 0; mt < 4; ++mt)
#pragma unroll
      for (int nt = 0; nt < 4; ++nt) { float4v z = {0.f,0.f,0.f,0.f}; acc[mt][nt] = z; }
    int pix[4];
#pragma unroll
    for (int nt = 0; nt < 4; ++nt) pix[nt] = s_pix[o][nt * 16 + ln];
    const int cbase = lg * 8;
#pragma unroll 1
    for (int s = 0; s < 19; ++s) {
      half8 bfr[4];
      if (s < 18) {
        int kb = s >> 1;
        int delta = (kb / 3) * 98 + (kb % 3);
        int coff = cbase + ((s & 1) << 5);
#pragma unroll
        for (int nt = 0; nt < 4; ++nt)
          bfr[nt] = *(const half8*)(P + (pix[nt] + delta) * 64 + coff);
      } else {
#pragma unroll
        for (int nt = 0; nt < 4; ++nt)
          bfr[nt] = *(const half8*)(&s_ext[o][nt * 16 + ln][0]);  // W rows >=580 are 0
      }
      half8 afr[4];
      const _Float16* pa = wp0 + (((s * 4 + lg) * 256) + wv * 64 + ln) * 8;
#pragma unroll
      for (int mt = 0; mt < 4; ++mt) afr[mt] = *(const half8*)(pa + mt * 128);
#pragma unroll
      for (int mt = 0; mt < 4; ++mt)
#pragma unroll
        for (int nt = 0; nt < 4; ++nt)
          acc[mt][nt] = __builtin_amdgcn_mfma_f32_16x16x32_f16(afr[mt], bfr[nt], acc[mt][nt], 0, 0, 0);
    }
    writeback(acc, bias0, s_h, wv, lg, ln);   // s_h not yet read this offset
    __syncthreads();

    // ---------------- layers 1..3: K = 256 --------------------------------
#pragma unroll 1
    for (int l = 0; l < 3; ++l) {
      const _Float16* wp = (l == 0) ? wp1 : (l == 1) ? wp2 : wp3;
      const float* bs = (l == 0) ? bias1 : (l == 1) ? bias2 : bias3;
#pragma unroll
      for (int mt = 0; mt < 4; ++mt)
#pragma unroll
        for (int nt = 0; nt < 4; ++nt) { float4v z = {0.f,0.f,0.f,0.f}; acc[mt][nt] = z; }
#pragma unroll 1
      for (int s = 0; s < 8; ++s) {
        half8 bfr[4];
#pragma unroll
        for (int nt = 0; nt < 4; ++nt)
          bfr[nt] = *(const half8*)(&s_h[nt * 16 + ln][s * 32 + lg * 8]);
        half8 afr[4];
        const _Float16* pa = wp + (((s * 4 + lg) * 256) + wv * 64 + ln) * 8;
#pragma unroll
        for (int mt = 0; mt < 4; ++mt) afr[mt] = *(const half8*)(pa + mt * 128);
#pragma unroll
        for (int mt = 0; mt < 4; ++mt)
#pragma unroll
          for (int nt = 0; nt < 4; ++nt)
            acc[mt][nt] = __builtin_amdgcn_mfma_f32_16x16x32_f16(afr[mt], bfr[nt], acc[mt][nt], 0, 0, 0);
      }
      __syncthreads();               // all reads of s_h done
      writeback(acc, bs, s_h, wv, lg, ln);
      __syncthreads();
    }

    // ---------------- layer 4: 256 -> 3 (padded 16); each wave 1 n-tile ---
    float4v a4 = {0.f, 0.f, 0.f, 0.f};
#pragma unroll 1
    for (int s = 0; s < 8; ++s) {
      half8 bfr = *(const half8*)(&s_h[wv * 16 + ln][s * 32 + lg * 8]);
      half8 afr = *(const half8*)(wp4 + (((s * 4 + lg) * 16) + ln) * 8);
      a4 = __builtin_amdgcn_mfma_f32_16x16x32_f16(afr, bfr, a4, 0, 0, 0);
    }
    if (lg == 0) {                   // lanes 0..15 hold out-ch 0..3 (regs 0..3)
      int r = wv * 16 + ln;
      float aw = s_area[3 - o][r];   // areas reversed across offsets
      float4v cur = *(float4v*)(&s_num[r][0]);
      cur[0] += a4[0] * aw; cur[1] += a4[1] * aw; cur[2] += a4[2] * aw;
      *(float4v*)(&s_num[r][0]) = cur;
    }
    __syncthreads();                 // s_h / s_num stable before next offset
  }

  // ---- final: out = tanh(num/den + b4) * 1.01, f32 ----
  if (t < 64) {
    int q = q0 + t;
    if (q < NQ) {
      float den = s_area[0][t] + s_area[1][t] + s_area[2][t] + s_area[3][t];
      int ob = (bb * NQ + q) * 3;
#pragma unroll
      for (int j = 0; j < 3; ++j) {
        float v = s_num[t][j] / den + bias4[j];
        out[ob + j] = tanhf(v) * 1.01f;
      }
    }
  }
}

// ---------------------------------------------------------------------------
extern "C" void kernel_launch(void* const* d_in, const int* in_sizes, int n_in,
                              void* d_out, int out_size, void* d_ws, size_t ws_size,
                              hipStream_t stream) {
  const float* inp   = (const float*)d_in[0];
  const float* coord = (const float*)d_in[1];
  const float* cell  = (const float*)d_in[2];
  const float* cw    = (const float*)d_in[3];
  const float* cb    = (const float*)d_in[4];
  const float* w0    = (const float*)d_in[5];
  const float* b0    = (const float*)d_in[6];
  const float* w1    = (const float*)d_in[7];
  const float* b1    = (const float*)d_in[8];
  const float* w2    = (const float*)d_in[9];
  const float* b2    = (const float*)d_in[10];
  const float* w3    = (const float*)d_in[11];
  const float* b3    = (const float*)d_in[12];
  const float* w4    = (const float*)d_in[13];
  const float* b4    = (const float*)d_in[14];

  char* ws = (char*)d_ws;
  _Float16* P   = (_Float16*)(ws);            // 2,458,624 B
  _Float16* wp0 = (_Float16*)(ws + 2458624);  //   311,296 B
  _Float16* wp1 = (_Float16*)(ws + 2769920);  //   131,072 B
  _Float16* wp2 = (_Float16*)(ws + 2900992);
  _Float16* wp3 = (_Float16*)(ws + 3032064);
  _Float16* wp4 = (_Float16*)(ws + 3163136);  //     8,192 B
  float* outp = (float*)d_out;

  hipLaunchKernelGGL(prep_kernel, dim3(1392), dim3(256), 0, stream,
                     w0, w1, w2, w3, w4, wp0, wp1, wp2, wp3, wp4);
  hipLaunchKernelGGL(conv_kernel, dim3(76), dim3(256), 0, stream, inp, cw, cb, P);
  hipLaunchKernelGGL(liif_main, dim3(2 * QT), dim3(256), 0, stream,
                     coord, cell, b0, b1, b2, b3, b4,
                     P, wp0, wp1, wp2, wp3, wp4, outp);
}

// Round 5
// 360.206 us; speedup vs baseline: 2.6185x; 1.2172x over previous
//
#include <hip/hip_runtime.h>

// ---------------------------------------------------------------------------
// LIIF forward, MI355X.  ALL tensors are float32 (per reference source).
// prep_kernel: weight repack f32->f16; layer0 rows permuted f' = k*64+c
//   (k=3x3 patch idx, c=channel), K padded 580->592 (kb 0..73); w4 N 3->16.
// conv_kernel: 3x3 conv (3->64) + bias + tanh -> padded map P[2][98][98][64].
// liif_main (R5 rewrite):
//   - 2 corner-offsets fused per pass: 128 activation rows between barriers
//     (16 barriers/WG vs 33), 2x weight reuse per fetch.
//   - layers 0-3 use mfma_f32_32x32x16_f16 (half the instructions, +17%
//     pipe efficiency vs 16x16x32); layer 4 keeps 16x16x32 (N=16 pad).
//     32x32 C/D layout (measured m74/m101): n=lane&31,
//     m=(reg&3)+8*(reg>>2)+4*(lane>>5).
//   - manual prefetch of next-step weight/gather fragments so vmcnt waits
//     overlap MFMA issue (R4 drained vmcnt(0) every K-step).
//   - biases staged to LDS; XCD batch partition (batch = bit2 of blockIdx,
//     grid 944) so each XCD L2 holds one batch's 2.4 MB feature map.
//   LDS 80,912 B -> 2 WG/CU.  __launch_bounds__(256,2): acc 128 AGPR +
//   ~90 arch VGPR fits budget 256 (R3 lesson: watch WRITE_SIZE for spills).
// ---------------------------------------------------------------------------

typedef _Float16 half8   __attribute__((ext_vector_type(8)));
typedef _Float16 half4v  __attribute__((ext_vector_type(4)));
typedef float    float4v __attribute__((ext_vector_type(4)));
typedef float    floatx16 __attribute__((ext_vector_type(16)));

// clamped f32->f16 (squashes NaN/inf at layer boundaries)
__device__ __forceinline__ _Float16 to_h(float v) {
  return (_Float16)fminf(fmaxf(v, -60000.0f), 60000.0f);
}

#define NQ 30000
#define QT 469   // ceil(NQ/64) real tiles per batch
#define QTP 472  // padded to 4-multiple for XCD-partitioned grid (944 blocks)

// ---------------- weight repack --------------------------------------------
// wp layout: [kb][n][8] f16, element (n, k=kb*8+i) at ((kb*N + n)*8 + i).
// wp0: kb 0..73 (K=592), rows f<576 permuted f = k*64+c <-> orig c*9+patch,
//      576<=f<580 direct (rel coords), f>=580 zero.
__global__ void prep_kernel(const float* __restrict__ w0,
                            const float* __restrict__ w1,
                            const float* __restrict__ w2,
                            const float* __restrict__ w3,
                            const float* __restrict__ w4,
                            _Float16* __restrict__ p0, _Float16* __restrict__ p1,
                            _Float16* __restrict__ p2, _Float16* __restrict__ p3,
                            _Float16* __restrict__ p4) {
  int idx = blockIdx.x * 256 + threadIdx.x;
  if (idx < 151552) {                      // wp0: 74 kb * 256 n * 8
    int kb = idx >> 11, rem = idx & 2047;
    int n = rem >> 3, i = rem & 7;
    int f = kb * 8 + i;                    // permuted feature index
    float v = 0.0f;
    if (f < 576)      v = w0[((f & 63) * 9 + (f >> 6)) * 256 + n];
    else if (f < 580) v = w0[f * 256 + n];
    p0[idx] = (_Float16)v;
  } else if (idx < 348160) {               // wp1..3: 3 * 32kb * 256 * 8
    int j = idx - 151552;
    int l = j >> 16;
    int j2 = j & 65535;
    int kb = j2 >> 11, rem = j2 & 2047;
    int n = rem >> 3, i = rem & 7;
    int k = kb * 8 + i;
    const float* w = (l == 0) ? w1 : (l == 1) ? w2 : w3;
    _Float16* p = (l == 0) ? p1 : (l == 1) ? p2 : p3;
    p[j2] = (_Float16)w[k * 256 + n];
  } else if (idx < 352256) {               // wp4: 32kb * 16 * 8
    int j = idx - 348160;
    int kb = j >> 7, rem = j & 127;
    int n = rem >> 3, i = rem & 7;
    int k = kb * 8 + i;
    float v = (n < 3) ? w4[k * 3 + n] : 0.0f;
    p4[j] = (_Float16)v;
  }
}

// ---------------- conv 3x3 (3->64) + bias + tanh, zero-padded borders ------
__global__ void conv_kernel(const float* __restrict__ inp,
                            const float* __restrict__ cw,
                            const float* __restrict__ cb,
                            _Float16* __restrict__ P) {
  __shared__ __align__(16) float s_w[1728];
  __shared__ __align__(16) float s_b[64];
  for (int i = threadIdx.x; i < 1728; i += 256) s_w[i] = cw[i];
  if (threadIdx.x < 64) s_b[threadIdx.x] = cb[threadIdx.x];
  __syncthreads();
  int tid = blockIdx.x * 256 + threadIdx.x;
  if (tid >= 2 * 98 * 98) return;
  int b = tid / 9604;
  int rem = tid % 9604;
  int yy = rem / 98, xx = rem % 98;
  alignas(16) _Float16 outv[64];
  if (yy == 0 || yy == 97 || xx == 0 || xx == 97) {
#pragma unroll
    for (int c = 0; c < 64; ++c) outv[c] = (_Float16)0.0f;
  } else {
    int y = yy - 1, x = xx - 1;
    float win[27];
#pragma unroll
    for (int ci = 0; ci < 3; ++ci)
#pragma unroll
      for (int ky = 0; ky < 3; ++ky)
#pragma unroll
        for (int kx = 0; kx < 3; ++kx) {
          int yi = y + ky - 1, xi = x + kx - 1;
          float v = 0.0f;
          if (yi >= 0 && yi < 96 && xi >= 0 && xi < 96)
            v = inp[((b * 3 + ci) * 96 + yi) * 96 + xi];
          win[ci * 9 + ky * 3 + kx] = v;
        }
    for (int co = 0; co < 64; ++co) {
      float acc = s_b[co];
#pragma unroll
      for (int k = 0; k < 27; ++k) acc = fmaf(win[k], s_w[co * 27 + k], acc);
      outv[co] = (_Float16)tanhf(acc);
    }
  }
  _Float16* dst = P + tid * 64;
#pragma unroll
  for (int j = 0; j < 8; ++j) ((half8*)dst)[j] = ((const half8*)outv)[j];
}

// ---------------- main: gather + MLP + blend -------------------------------
// WG = 256 thr = 4 waves = 64 queries x 2 offsets (128 rows) per pass.
// Transposed GEMMs D = W^T x^T; A = packed weights, B = activation rows.
// 32x32x16: wave wv owns m-tiles {2wv,2wv+1} (64 ch), all 4 n-tiles.
__device__ __forceinline__ void writeback32(floatx16 (&acc)[2][4],
                                            const float* __restrict__ sb,
                                            _Float16 (*s_h)[264],
                                            int wv, int ln32, int hi) {
#pragma unroll
  for (int mt2 = 0; mt2 < 2; ++mt2) {
    const int mb = wv * 64 + mt2 * 32 + 4 * hi;
#pragma unroll
    for (int g = 0; g < 4; ++g) {
      const int m0 = mb + 8 * g;
      float b0 = sb[m0], b1 = sb[m0 + 1], b2 = sb[m0 + 2], b3 = sb[m0 + 3];
#pragma unroll
      for (int nt2 = 0; nt2 < 4; ++nt2) {
        const int n = nt2 * 32 + ln32;
        half4v hv;
        hv[0] = to_h(fmaxf(acc[mt2][nt2][4 * g + 0] + b0, 0.0f));
        hv[1] = to_h(fmaxf(acc[mt2][nt2][4 * g + 1] + b1, 0.0f));
        hv[2] = to_h(fmaxf(acc[mt2][nt2][4 * g + 2] + b2, 0.0f));
        hv[3] = to_h(fmaxf(acc[mt2][nt2][4 * g + 3] + b3, 0.0f));
        *(half4v*)(&s_h[n][m0]) = hv;
      }
    }
  }
}

__global__ __launch_bounds__(256, 2) void liif_main(
    const float* __restrict__ coord, const float* __restrict__ cell,
    const float* __restrict__ bias0, const float* __restrict__ bias1,
    const float* __restrict__ bias2, const float* __restrict__ bias3,
    const float* __restrict__ bias4,
    const _Float16* __restrict__ P,
    const _Float16* __restrict__ wp0, const _Float16* __restrict__ wp1,
    const _Float16* __restrict__ wp2, const _Float16* __restrict__ wp3,
    const _Float16* __restrict__ wp4,
    float* __restrict__ out) {
  __shared__ __align__(16) int      s_pix[4][64];
  __shared__ __align__(16) float    s_area[4][64];
  __shared__ __align__(16) _Float16 s_ext[4][64][8];
  __shared__ __align__(16) float    s_bias[1028];
  __shared__ __align__(16) float    s_out[128][4];
  __shared__ __align__(16) float    s_num[64][4];
  __shared__ __align__(16) _Float16 s_h[128][264]; // stride 132 dw = 4 mod 32

  const int t   = threadIdx.x;
  const int blk = blockIdx.x;
  const int bb  = (blk & 4) >> 2;            // batch = bit2 -> stable per XCD
  const int tile = (blk >> 3) * 4 + (blk & 3);
  const int q0  = tile * 64;

  // ---- stage biases into LDS (1027 f32) ----
  for (int i = t; i < 1027; i += 256) {
    float v;
    if (i < 256)       v = bias0[i];
    else if (i < 512)  v = bias1[i - 256];
    else if (i < 768)  v = bias2[i - 512];
    else if (i < 1024) v = bias3[i - 768];
    else               v = bias4[i - 1024];
    s_bias[i] = v;
  }

  // ---- phase 0: per-row meta for all 4 offsets (f32, matches np) ----
  if (t < 64) {
    int q = q0 + t;
    bool valid = q < NQ;
    float c0 = 0.f, c1 = 0.f, e0 = 0.f, e1 = 0.f;
    if (valid) {
      int base = (bb * NQ + q) * 2;
      c0 = coord[base]; c1 = coord[base + 1];
      e0 = cell[base];  e1 = cell[base + 1];
    }
    float rc0 = e0 * 96.0f, rc1 = e1 * 96.0f;
#pragma unroll
    for (int o = 0; o < 4; ++o) {
      float oy = (o < 2) ? -1.0f : 1.0f;     // offsets [-1,-1],[-1,1],[1,-1],[1,1]
      float ox = (o & 1) ? 1.0f : -1.0f;
      float ec0 = (c0 + oy * (1.0f / 96.0f)) + 1e-6f;
      float ec1 = (c1 + ox * (1.0f / 96.0f)) + 1e-6f;
      ec0 = fminf(fmaxf(ec0, -1.0f), 1.0f);  // f32(-1+1e-10) == -1.0f
      ec1 = fminf(fmaxf(ec1, -1.0f), 1.0f);
      int iy = (int)rintf(((ec0 + 1.0f) * 96.0f) * 0.5f - 0.5f);  // half-even
      int ix = (int)rintf(((ec1 + 1.0f) * 96.0f) * 0.5f - 0.5f);
      iy = min(max(iy, 0), 95); ix = min(max(ix, 0), 95);
      float qc0 = -1.0f + (2.0f * (float)iy + 1.0f) / 96.0f;
      float qc1 = -1.0f + (2.0f * (float)ix + 1.0f) / 96.0f;
      float r0 = (c0 - qc0) * 96.0f;
      float r1 = (c1 - qc1) * 96.0f;
      s_pix[o][t]  = (bb * 98 + iy) * 98 + ix;   // padded pixel base
      s_area[o][t] = fabsf(r0 * r1) + 1e-9f;
      s_ext[o][t][0] = to_h(r0);  s_ext[o][t][1] = to_h(r1);
      s_ext[o][t][2] = to_h(rc0); s_ext[o][t][3] = to_h(rc1);
      s_ext[o][t][4] = (_Float16)0.0f; s_ext[o][t][5] = (_Float16)0.0f;
      s_ext[o][t][6] = (_Float16)0.0f; s_ext[o][t][7] = (_Float16)0.0f;
    }
    s_num[t][0] = 0.f; s_num[t][1] = 0.f; s_num[t][2] = 0.f; s_num[t][3] = 0.f;
  }
  __syncthreads();

  const int lane = t & 63;
  const int wv   = t >> 6;
  const int ln32 = lane & 31;
  const int hi   = lane >> 5;
  const int ln16 = lane & 15;
  const int lg   = lane >> 4;

#pragma unroll 1
  for (int p = 0; p < 2; ++p) {
    // per-n-tile row meta: row r = nt2*32+ln32, offset = 2p + (r>>6), q = r&63
    int pixr[4]; int eidx[4];
#pragma unroll
    for (int nt2 = 0; nt2 < 4; ++nt2) {
      int r = nt2 * 32 + ln32;
      int o = p * 2 + (r >> 6);
      int q = r & 63;
      pixr[nt2] = s_pix[o][q];
      eidx[nt2] = (o * 64 + q) * 8;
    }

    // ---------------- layer 0: K = 592 = 37 x 16 (36 gather + 1 ext) ------
    floatx16 acc[2][4];
#pragma unroll
    for (int mt2 = 0; mt2 < 2; ++mt2)
#pragma unroll
      for (int nt2 = 0; nt2 < 4; ++nt2) acc[mt2][nt2] = (floatx16)(0.0f);

    half8 bfc[4], afc[2];
#pragma unroll
    for (int nt2 = 0; nt2 < 4; ++nt2)
      bfc[nt2] = *(const half8*)(P + pixr[nt2] * 64 + hi * 8);
#pragma unroll
    for (int mt2 = 0; mt2 < 2; ++mt2)
      afc[mt2] = *(const half8*)(wp0 + (hi * 256 + wv * 64 + mt2 * 32 + ln32) * 8);

#pragma unroll 1
    for (int s = 0; s < 37; ++s) {
      half8 bfn[4], afn[2];
      int sn = s + 1;
      if (sn < 37) {
        if (sn < 36) {
          int patch = sn >> 2;
          int delta = (patch / 3) * 98 + (patch % 3);
          int coff  = ((sn & 3) << 4) + hi * 8;
#pragma unroll
          for (int nt2 = 0; nt2 < 4; ++nt2)
            bfn[nt2] = *(const half8*)(P + (pixr[nt2] + delta) * 64 + coff);
        } else {  // ext block: k 576-591, upper half zero
#pragma unroll
          for (int nt2 = 0; nt2 < 4; ++nt2) {
            half8 z = {(_Float16)0, (_Float16)0, (_Float16)0, (_Float16)0,
                       (_Float16)0, (_Float16)0, (_Float16)0, (_Float16)0};
            bfn[nt2] = hi == 0 ? *(const half8*)(&s_ext[0][0][0] + eidx[nt2]) : z;
          }
        }
        int kbn = sn * 2 + hi;
#pragma unroll
        for (int mt2 = 0; mt2 < 2; ++mt2)
          afn[mt2] = *(const half8*)(wp0 + (kbn * 256 + wv * 64 + mt2 * 32 + ln32) * 8);
      }
#pragma unroll
      for (int mt2 = 0; mt2 < 2; ++mt2)
#pragma unroll
        for (int nt2 = 0; nt2 < 4; ++nt2)
          acc[mt2][nt2] = __builtin_amdgcn_mfma_f32_32x32x16_f16(afc[mt2], bfc[nt2], acc[mt2][nt2], 0, 0, 0);
      if (sn < 37) {
#pragma unroll
        for (int nt2 = 0; nt2 < 4; ++nt2) bfc[nt2] = bfn[nt2];
        afc[0] = afn[0]; afc[1] = afn[1];
      }
    }
    writeback32(acc, s_bias, s_h, wv, ln32, hi);  // prior L4 reads synced
    __syncthreads();

    // ---------------- layers 1..3: K = 256 = 16 x 16 ----------------------
#pragma unroll 1
    for (int l = 0; l < 3; ++l) {
      const _Float16* wp = (l == 0) ? wp1 : (l == 1) ? wp2 : wp3;
      const float* sb = s_bias + (l + 1) * 256;
#pragma unroll
      for (int mt2 = 0; mt2 < 2; ++mt2)
#pragma unroll
        for (int nt2 = 0; nt2 < 4; ++nt2) acc[mt2][nt2] = (floatx16)(0.0f);
#pragma unroll
      for (int mt2 = 0; mt2 < 2; ++mt2)
        afc[mt2] = *(const half8*)(wp + (hi * 256 + wv * 64 + mt2 * 32 + ln32) * 8);
#pragma unroll 1
      for (int s = 0; s < 16; ++s) {
        half8 bfr[4];
#pragma unroll
        for (int nt2 = 0; nt2 < 4; ++nt2)
          bfr[nt2] = *(const half8*)(&s_h[nt2 * 32 + ln32][s * 16 + hi * 8]);
        half8 afn[2];
        if (s < 15) {
          int kbn = (s + 1) * 2 + hi;
#pragma unroll
          for (int mt2 = 0; mt2 < 2; ++mt2)
            afn[mt2] = *(const half8*)(wp + (kbn * 256 + wv * 64 + mt2 * 32 + ln32) * 8);
        }
#pragma unroll
        for (int mt2 = 0; mt2 < 2; ++mt2)
#pragma unroll
          for (int nt2 = 0; nt2 < 4; ++nt2)
            acc[mt2][nt2] = __builtin_amdgcn_mfma_f32_32x32x16_f16(afc[mt2], bfr[nt2], acc[mt2][nt2], 0, 0, 0);
        if (s < 15) { afc[0] = afn[0]; afc[1] = afn[1]; }
      }
      __syncthreads();               // all reads of s_h done
      writeback32(acc, sb, s_h, wv, ln32, hi);
      __syncthreads();
    }

    // ---------------- layer 4: 256 -> 3 (16x16x32, N padded 16) -----------
    // wave wv handles n-tiles {2wv, 2wv+1} (rows 32wv..32wv+31)
    float4v a4[2];
    a4[0] = (float4v){0.f, 0.f, 0.f, 0.f};
    a4[1] = (float4v){0.f, 0.f, 0.f, 0.f};
#pragma unroll 1
    for (int s = 0; s < 8; ++s) {
      half8 af = *(const half8*)(wp4 + (((s * 4 + lg) * 16) + ln16) * 8);
#pragma unroll
      for (int u = 0; u < 2; ++u) {
        int row = (2 * wv + u) * 16 + ln16;
        half8 bf = *(const half8*)(&s_h[row][s * 32 + lg * 8]);
        a4[u] = __builtin_amdgcn_mfma_f32_16x16x32_f16(af, bf, a4[u], 0, 0, 0);
      }
    }
    if (lg == 0) {                   // lanes 0..15: out-ch j = reg j
#pragma unroll
      for (int u = 0; u < 2; ++u) {
        int row = (2 * wv + u) * 16 + ln16;
        *(float4v*)(&s_out[row][0]) = a4[u];
      }
    }
    __syncthreads();                 // s_out ready; s_h reads done

    if (t < 64) {                    // blend this pass's 2 offsets
      float a_lo = s_area[3 - 2 * p][t];      // rows 0-63:  o = 2p
      float a_hi = s_area[2 - 2 * p][t];      // rows 64-127: o = 2p+1
#pragma unroll
      for (int j = 0; j < 3; ++j)
        s_num[t][j] += s_out[t][j] * a_lo + s_out[64 + t][j] * a_hi;
    }
  }

  // ---- final: out = tanh(num/den + b4) * 1.01, f32 ----
  if (t < 64) {
    int q = q0 + t;
    if (q < NQ) {
      float den = s_area[0][t] + s_area[1][t] + s_area[2][t] + s_area[3][t];
      int ob = (bb * NQ + q) * 3;
#pragma unroll
      for (int j = 0; j < 3; ++j) {
        float v = s_num[t][j] / den + s_bias[1024 + j];
        out[ob + j] = tanhf(v) * 1.01f;
      }
    }
  }
}

// ---------------------------------------------------------------------------
extern "C" void kernel_launch(void* const* d_in, const int* in_sizes, int n_in,
                              void* d_out, int out_size, void* d_ws, size_t ws_size,
                              hipStream_t stream) {
  const float* inp   = (const float*)d_in[0];
  const float* coord = (const float*)d_in[1];
  const float* cell  = (const float*)d_in[2];
  const float* cw    = (const float*)d_in[3];
  const float* cb    = (const float*)d_in[4];
  const float* w0    = (const float*)d_in[5];
  const float* b0    = (const float*)d_in[6];
  const float* w1    = (const float*)d_in[7];
  const float* b1    = (const float*)d_in[8];
  const float* w2    = (const float*)d_in[9];
  const float* b2    = (const float*)d_in[10];
  const float* w3    = (const float*)d_in[11];
  const float* b3    = (const float*)d_in[12];
  const float* w4    = (const float*)d_in[13];
  const float* b4    = (const float*)d_in[14];

  char* ws = (char*)d_ws;
  _Float16* P   = (_Float16*)(ws);            // 2,458,624 B
  _Float16* wp0 = (_Float16*)(ws + 2458624);  //   303,104 B (74 kb)
  _Float16* wp1 = (_Float16*)(ws + 2761728);  //   131,072 B
  _Float16* wp2 = (_Float16*)(ws + 2892800);
  _Float16* wp3 = (_Float16*)(ws + 3023872);
  _Float16* wp4 = (_Float16*)(ws + 3154944);  //     8,192 B
  float* outp = (float*)d_out;

  hipLaunchKernelGGL(prep_kernel, dim3(1376), dim3(256), 0, stream,
                     w0, w1, w2, w3, w4, wp0, wp1, wp2, wp3, wp4);
  hipLaunchKernelGGL(conv_kernel, dim3(76), dim3(256), 0, stream, inp, cw, cb, P);
  hipLaunchKernelGGL(liif_main, dim3(8 * (QTP / 4)), dim3(256), 0, stream,
                     coord, cell, b0, b1, b2, b3, b4,
                     P, wp0, wp1, wp2, wp3, wp4, outp);
}